// Round 10
// baseline (225.215 us; speedup 1.0000x reference)
//
#include <hip/hip_runtime.h>

typedef __bf16 bf16x8 __attribute__((ext_vector_type(8)));
typedef float f32x4 __attribute__((ext_vector_type(4)));

#define MFMA(a, b, c) __builtin_amdgcn_mfma_f32_16x16x32_bf16((a), (b), (c), 0, 0, 0)

// DPP cross-lane (16-lane row reduce): quad_perm xor1=0xB1, xor2=0x4E, row_ror:4=0x124, row_ror:8=0x128
#define DPPF(x, ctrl) __builtin_bit_cast(float, __builtin_amdgcn_mov_dpp(__builtin_bit_cast(int, (x)), (ctrl), 0xF, 0xF, true))

static __device__ __forceinline__ float rowmax16(float v) {
    v = fmaxf(v, DPPF(v, 0xB1));
    v = fmaxf(v, DPPF(v, 0x4E));
    v = fmaxf(v, DPPF(v, 0x124));
    v = fmaxf(v, DPPF(v, 0x128));
    return v;
}
static __device__ __forceinline__ float rowsum16(float v) {
    v += DPPF(v, 0xB1);
    v += DPPF(v, 0x4E);
    v += DPPF(v, 0x124);
    v += DPPF(v, 0x128);
    return v;
}

static __device__ __forceinline__ unsigned short f2b(float f) {
    // fp32 -> bf16, round-to-nearest-even
    unsigned int u = __builtin_bit_cast(unsigned int, f);
    unsigned int lsb = (u >> 16) & 1u;
    u += 0x7fffu + lsb;
    return (unsigned short)(u >> 16);
}

static __device__ __forceinline__ f32x4 zero4() {
    f32x4 z; z[0] = 0.f; z[1] = 0.f; z[2] = 0.f; z[3] = 0.f; return z;
}

// async global->LDS, 16B per lane; LDS dest = wave-uniform base + lane*16
typedef __attribute__((address_space(3))) unsigned int lds_as_t;
typedef const __attribute__((address_space(1))) unsigned int glb_as_t;
static __device__ __forceinline__ void gload16(const void* g, void* l) {
    __builtin_amdgcn_global_load_lds((glb_as_t*)g, (lds_as_t*)l, 16, 0, 0);
}

// ---------------------------------------------------------------------------
// prep_convert: one BW-bound pass (unchanged from round 8).
// ---------------------------------------------------------------------------
__global__ __launch_bounds__(256) void prep_convert(
    const float* __restrict__ q, const float* __restrict__ k, const float* __restrict__ v,
    const float* __restrict__ wq, const float* __restrict__ wk, const float* __restrict__ wv,
    const float* __restrict__ rel, const float* __restrict__ vrel,
    unsigned short* __restrict__ xq, unsigned short* __restrict__ xk, unsigned short* __restrict__ xv,
    unsigned short* __restrict__ wqb, unsigned short* __restrict__ wkb, unsigned short* __restrict__ wvb,
    unsigned short* __restrict__ erb, unsigned short* __restrict__ ervT)
{
    const int NG = 2375680;  // float4 groups total
    for (int g = blockIdx.x * 256 + threadIdx.x; g < NG + 69632; g += gridDim.x * 256) {
        if (g < NG) {
            const float* src; unsigned short* dst; int off;
            if (g < 1572864) {
                int s = g / 524288; off = g - s * 524288;
                src = s == 0 ? q : s == 1 ? k : v;
                dst = s == 0 ? xq : s == 1 ? xk : xv;
            } else if (g < 2359296) {
                int s = (g - 1572864) / 262144; off = g - 1572864 - s * 262144;
                src = s == 0 ? wq : s == 1 ? wk : wv;
                dst = s == 0 ? wqb : s == 1 ? wkb : wvb;
            } else {
                off = g - 2359296; src = rel; dst = erb;
            }
            float4 x = *(const float4*)(src + (size_t)off * 4);
            *(ushort4*)(dst + (size_t)off * 4) =
                make_ushort4(f2b(x.x), f2b(x.y), f2b(x.z), f2b(x.w));
        } else {
            int j = g - NG;
            int dh = j / 1088, c = j % 1088, r = c - 47;
            ervT[j] = (r >= 0 && r < 1024) ? f2b(vrel[r * 64 + dh]) : (unsigned short)0;
        }
    }
}

// ---------------------------------------------------------------------------
// proj_gemm2: fused M=6144 GEMM (z = mt>>4 selects q/k/v), unchanged.
// ---------------------------------------------------------------------------
__global__ __launch_bounds__(256, 4) void proj_gemm2(
    const unsigned short* __restrict__ xq, const unsigned short* __restrict__ xk,
    const unsigned short* __restrict__ xv,
    const unsigned short* __restrict__ wqb, const unsigned short* __restrict__ wkb,
    const unsigned short* __restrict__ wvb,
    const float* __restrict__ bqp, const float* __restrict__ bkp, const float* __restrict__ bvp,
    unsigned short* __restrict__ oq, unsigned short* __restrict__ ok, unsigned short* __restrict__ ov)
{
    __shared__ unsigned short As[128][64];
    __shared__ unsigned short Bs[64][64];

    const int tid = threadIdx.x, lane = tid & 63, w = tid >> 6;
    const int bid = blockIdx.x;
    const int swz = (bid & 7) * 96 + (bid >> 3);      // bijective XCD swizzle
    const int mt = swz >> 4, nt = swz & 15;
    const int z = mt >> 4;
    const int mm0 = (mt & 15) * 128, n0 = nt * 64;

    const unsigned short* X = z == 0 ? xq : z == 1 ? xk : xv;
    const unsigned short* W = z == 0 ? wqb : z == 1 ? wkb : wvb;
    const float* bias = z == 0 ? bqp : z == 1 ? bkp : bvp;
    unsigned short* outp = z == 0 ? oq : z == 1 ? ok : ov;

    const int wm = (w & 1) * 64, wn = (w >> 1) * 32;
    const int lr = lane & 15, lg = lane >> 4;
    const int arow = lane >> 3, acol = (lane & 7) * 8;

    f32x4 acc[4][2];
#pragma unroll
    for (int a = 0; a < 4; ++a)
#pragma unroll
        for (int bq = 0; bq < 2; ++bq) acc[a][bq] = zero4();

    for (int k0 = 0; k0 < 1024; k0 += 64) {
#pragma unroll
        for (int c = 0; c < 4; ++c) {
            int ch = w + c * 4;
            gload16(X + (size_t)(mm0 + ch * 8 + arow) * 1024 + k0 + acol, &As[ch * 8][0]);
        }
#pragma unroll
        for (int c = 0; c < 2; ++c) {
            int ch = w + c * 4;
            gload16(W + (size_t)(n0 + ch * 8 + arow) * 1024 + k0 + acol, &Bs[ch * 8][0]);
        }
        __syncthreads();

        bf16x8 af[4][2], bg[2][2];
#pragma unroll
        for (int m4 = 0; m4 < 4; ++m4)
#pragma unroll
            for (int ks = 0; ks < 2; ++ks)
                af[m4][ks] = *(const bf16x8*)&As[wm + m4 * 16 + lr][ks * 32 + lg * 8];
#pragma unroll
        for (int n2 = 0; n2 < 2; ++n2)
#pragma unroll
            for (int ks = 0; ks < 2; ++ks)
                bg[n2][ks] = *(const bf16x8*)&Bs[wn + n2 * 16 + lr][ks * 32 + lg * 8];
#pragma unroll
        for (int m4 = 0; m4 < 4; ++m4)
#pragma unroll
            for (int n2 = 0; n2 < 2; ++n2)
#pragma unroll
                for (int ks = 0; ks < 2; ++ks)
                    acc[m4][n2] = MFMA(af[m4][ks], bg[n2][ks], acc[m4][n2]);
        __syncthreads();
    }

#pragma unroll
    for (int m4 = 0; m4 < 4; ++m4)
#pragma unroll
        for (int n2 = 0; n2 < 2; ++n2)
#pragma unroll
            for (int r = 0; r < 4; ++r) {
                int mrow = mm0 + wm + m4 * 16 + lg * 4 + r;
                int n = n0 + wn + n2 * 16 + lr;
                float vv = acc[m4][n2][r] + bias[n];
                if (z == 0) vv *= 0.125f;          // fold score scale into Q (exact)
                int b = mrow >> 10, s = mrow & 1023, h = n >> 6, dh = n & 63;
                unsigned short bv = f2b(vv);
                if (z == 2)
                    outp[(((size_t)(b * 16 + h)) * 64 + dh) * 1024 + s] = bv;
                else
                    outp[(((size_t)(b * 16 + h)) * 1024 + s) * 64 + dh] = bv;
            }
}

// ---------------------------------------------------------------------------
// Fused causal attention with relative-position bias (scores and values).
// Software-pipelined tile loop (hand-unrolled x2, static register sets A/B,
// rule #20). K+er fragments prefetched ONE TILE AHEAD; V+ervT fragments
// issued at compute top (~500cy before PV use). launch_bounds (256,1) so the
// ~200-VGPR payload stays in registers (round-8: VGPR=100 -> serialized
// loads, 28K cy/tile). Q arrives pre-scaled by 0.125 from proj (exact).
// ---------------------------------------------------------------------------
#define LOAD_KE(S, TI) do {                                                        \
    int j0_ = (TI) * 32;                                                           \
    int dbp_ = i0 - j0_ - 31;                                                      \
    dbp##S = dbp_; j0##S = j0_;                                                    \
    _Pragma("unroll")                                                              \
    for (int ct = 0; ct < 2; ++ct) {                                               \
        const unsigned short* kbase =                                              \
            kb + (((size_t)bh * 1024) + j0_ + ct * 16 + lr) * 64 + lg * 8;         \
        kf##S[ct][0] = *(const bf16x8*)kbase;                                      \
        kf##S[ct][1] = *(const bf16x8*)(kbase + 32);                               \
    }                                                                              \
    _Pragma("unroll")                                                              \
    for (int st = 0; st < 3; ++st) {                                               \
        int dr = dbp_ + st * 16 + lr;                                              \
        dr = dr < 0 ? 0 : (dr > 1023 ? 1023 : dr);                                 \
        const unsigned short* eb = erb + (size_t)dr * 64 + lg * 8;                 \
        ef##S[st][0] = *(const bf16x8*)eb;                                         \
        ef##S[st][1] = *(const bf16x8*)(eb + 32);                                  \
    }                                                                              \
} while (0)

#define COMPUTE_TILE(S) do {                                                       \
    const int j0_ = j0##S, dbp_ = dbp##S;                                          \
    /* V + ervT issued first: used only by PV ~500cy later */                      \
    bf16x8 vf[4], rf[4][2];                                                        \
    _Pragma("unroll")                                                              \
    for (int dt = 0; dt < 4; ++dt)                                                 \
        vf[dt] = *(const bf16x8*)(vtb + ((size_t)bh * 64 + dt * 16 + lr) * 1024 + j0_ + lg * 8); \
    _Pragma("unroll")                                                              \
    for (int dt = 0; dt < 4; ++dt) {                                               \
        const unsigned short* rb2 =                                                \
            ervT + (size_t)(dt * 16 + lr) * 1088 + 47 + dbp_ + lg * 8;             \
        rf[dt][0] = *(const bf16x8*)rb2;                                           \
        rf[dt][1] = *(const bf16x8*)(rb2 + 32);                                    \
    }                                                                              \
    f32x4 sacc[2]; sacc[0] = zero4(); sacc[1] = zero4();                           \
    _Pragma("unroll")                                                              \
    for (int ct = 0; ct < 2; ++ct) {                                               \
        sacc[ct] = MFMA(qf0, kf##S[ct][0], sacc[ct]);                              \
        sacc[ct] = MFMA(qf1, kf##S[ct][1], sacc[ct]);                              \
    }                                                                              \
    f32x4 qeacc[3];                                                                \
    _Pragma("unroll")                                                              \
    for (int st = 0; st < 3; ++st) {                                               \
        qeacc[st] = zero4();                                                       \
        qeacc[st] = MFMA(qf0, ef##S[st][0], qeacc[st]);                            \
        qeacc[st] = MFMA(qf1, ef##S[st][1], qeacc[st]);                            \
    }                                                                              \
    _Pragma("unroll")                                                              \
    for (int st = 0; st < 3; ++st)                                                 \
        _Pragma("unroll")                                                          \
        for (int r = 0; r < 4; ++r)                                                \
            qe_w[(lg * 4 + r) * 50 + st * 16 + lr] = qeacc[st][r];                 \
    float sc2[2][4];                                                               \
    _Pragma("unroll")                                                              \
    for (int ct = 0; ct < 2; ++ct)                                                 \
        _Pragma("unroll")                                                          \
        for (int r = 0; r < 4; ++r) {                                              \
            int row  = lg * 4 + r;                                                 \
            int jcol = ct * 16 + lr;                                               \
            int t    = row - jcol + 31;                                            \
            float sc = sacc[ct][r] + qe_w[row * 50 + t];                           \
            if (j0_ + jcol > i0 + row) sc = -1e38f;                                \
            sc2[ct][r] = sc;                                                       \
        }                                                                          \
    float p2[2][4];                                                                \
    _Pragma("unroll")                                                              \
    for (int r = 0; r < 4; ++r) {                                                  \
        float mx = rowmax16(fmaxf(sc2[0][r], sc2[1][r]));                          \
        float mnew = fmaxf(m_run[r], mx);                                          \
        float scale = __expf(m_run[r] - mnew);                                     \
        float p0 = __expf(sc2[0][r] - mnew);                                       \
        float p1 = __expf(sc2[1][r] - mnew);                                       \
        float ps = rowsum16(p0 + p1);                                              \
        l_run[r] = l_run[r] * scale + ps;                                          \
        m_run[r] = mnew;                                                           \
        _Pragma("unroll")                                                          \
        for (int dt = 0; dt < 4; ++dt) oacc[dt][r] *= scale;                       \
        p2[0][r] = p0; p2[1][r] = p1;                                              \
    }                                                                              \
    _Pragma("unroll")                                                              \
    for (int ct = 0; ct < 2; ++ct)                                                 \
        _Pragma("unroll")                                                          \
        for (int r = 0; r < 4; ++r) {                                              \
            int row = lg * 4 + r, col = ct * 16 + lr;                              \
            unsigned short pb = f2b(p2[ct][r]);                                    \
            p_w[row * 32 + col] = pb;                                              \
            prv_w[row * 64 + (row + 31 - col)] = pb;                               \
        }                                                                          \
    bf16x8 pa   = *(const bf16x8*)&p_w[lr * 32 + lg * 8];                          \
    bf16x8 pra0 = *(const bf16x8*)&prv_w[lr * 64 + lg * 8];                        \
    bf16x8 pra1 = *(const bf16x8*)&prv_w[lr * 64 + 32 + lg * 8];                   \
    _Pragma("unroll")                                                              \
    for (int dt = 0; dt < 4; ++dt) {                                               \
        oacc[dt] = MFMA(pa, vf[dt], oacc[dt]);                                     \
        oacc[dt] = MFMA(pra0, rf[dt][0], oacc[dt]);                                \
        oacc[dt] = MFMA(pra1, rf[dt][1], oacc[dt]);                                \
    }                                                                              \
} while (0)

__global__ __launch_bounds__(256, 1) void attn_kernel(
    const unsigned short* __restrict__ qb, const unsigned short* __restrict__ kb,
    const unsigned short* __restrict__ vtb, const unsigned short* __restrict__ erb,
    const unsigned short* __restrict__ ervT, float* __restrict__ out)
{
    const int bx = blockIdx.x, h = blockIdx.y, b = blockIdx.z;
    const int bh = b * 16 + h;
    const int tid = threadIdx.x;
    const int lane = tid & 63, w = tid >> 6;
    const int lr = lane & 15, lg = lane >> 4;

    // Layout: [0,12800) qe (4 x [16][50] f32) | [12800,16896) p (4 x [16][32] u16)
    //         [16896,17408) pm/pl | [17408,25600) prv (4 x [16][64] u16)
    // Combine-phase pO = [0,16384) f32 (after barrier; never touches pm/pl/prv).
    __shared__ __align__(16) char smem[25600];
    float* qe_w = (float*)(smem + w * 3200);                             // [16][50]
    unsigned short* p_w   = (unsigned short*)(smem + 12800 + w * 1024);  // [16][32]
    unsigned short* prv_w = (unsigned short*)(smem + 17408 + w * 2048);  // [16][64]
    float* pO = (float*)smem;              // [4][16][64]
    float* pm = (float*)(smem + 16896);    // [4][16]
    float* pl = pm + 64;                   // [4][16]

    // zero own prv slice once; unwritten slots stay zero forever
    for (int t = lane; t < 16 * 64; t += 64) prv_w[t] = 0;

    for (int seg = 0; seg < 2; ++seg) {
        const int qt = seg == 0 ? bx : 63 - bx;
        const int i0 = qt * 16;

        const unsigned short* qbase = qb + (((size_t)bh * 1024) + i0 + lr) * 64 + lg * 8;
        const bf16x8 qf0 = *(const bf16x8*)qbase;         // dh 0..31 (pre-scaled 1/8)
        const bf16x8 qf1 = *(const bf16x8*)(qbase + 32);  // dh 32..63

        f32x4 oacc[4];
        float m_run[4], l_run[4];
#pragma unroll
        for (int r = 0; r < 4; ++r) { oacc[r] = zero4(); m_run[r] = -1e30f; l_run[r] = 0.f; }

        const int ntiles = qt / 2 + 1;
        bf16x8 kfA[2][2], efA[3][2], kfB[2][2], efB[3][2];
        int dbpA, j0A, dbpB, j0B;

        int ti = w;
        if (ti < ntiles) {
            LOAD_KE(A, ti);
            while (true) {
                int tn = ti + 4;
                if (tn < ntiles) LOAD_KE(B, tn);
                COMPUTE_TILE(A);
                if (tn >= ntiles) break;
                ti = tn; tn = ti + 4;
                if (tn < ntiles) LOAD_KE(A, tn);
                COMPUTE_TILE(B);
                if (tn >= ntiles) break;
                ti = tn;
            }
        }

        // ---- merge the 4 wave-partials via LDS --------------------------
        __syncthreads();  // loop-phase LDS reads done before pO overwrites
#pragma unroll
        for (int dt = 0; dt < 4; ++dt)
#pragma unroll
            for (int r = 0; r < 4; ++r)
                pO[w * 1024 + (lg * 4 + r) * 64 + dt * 16 + lr] = oacc[dt][r];
        if (lr == 0)
#pragma unroll
            for (int r = 0; r < 4; ++r) {
                pm[w * 16 + lg * 4 + r] = m_run[r];
                pl[w * 16 + lg * 4 + r] = l_run[r];
            }
        __syncthreads();

        // 16x64 outputs over 256 threads (4 cells each)
#pragma unroll
        for (int k = 0; k < 4; ++k) {
            int c = k * 256 + tid;
            int row = c >> 6, dh = c & 63;
            float m0 = pm[row], m1 = pm[16 + row], m2 = pm[32 + row], m3 = pm[48 + row];
            float mf = fmaxf(fmaxf(m0, m1), fmaxf(m2, m3));
            float e0 = __expf(m0 - mf), e1 = __expf(m1 - mf);
            float e2 = __expf(m2 - mf), e3 = __expf(m3 - mf);
            float den = e0 * pl[row] + e1 * pl[16 + row] + e2 * pl[32 + row] + e3 * pl[48 + row];
            float num = e0 * pO[row * 64 + dh]        + e1 * pO[1024 + row * 64 + dh]
                      + e2 * pO[2048 + row * 64 + dh] + e3 * pO[3072 + row * 64 + dh];
            out[((size_t)(b * 1024 + i0 + row)) * 1024 + h * 64 + dh] = num / den;
        }
        __syncthreads();  // pO reads done before next segment's qe writes
    }
}

// ---------------------------------------------------------------------------
extern "C" void kernel_launch(void* const* d_in, const int* in_sizes, int n_in,
                              void* d_out, int out_size, void* d_ws, size_t ws_size,
                              hipStream_t stream) {
    const float* query = (const float*)d_in[0];
    const float* key   = (const float*)d_in[1];
    const float* value = (const float*)d_in[2];
    const float* Wq    = (const float*)d_in[3];
    const float* bq    = (const float*)d_in[4];
    const float* Wk    = (const float*)d_in[5];
    const float* bk    = (const float*)d_in[6];
    const float* Wv    = (const float*)d_in[7];
    const float* bv    = (const float*)d_in[8];
    const float* rel   = (const float*)d_in[9];
    const float* vrel  = (const float*)d_in[10];
    float* out = (float*)d_out;

    char* w = (char*)d_ws;
    unsigned short* qb   = (unsigned short*)(w);              // 4 MiB  [B,H,S,Dh] (Q pre-scaled 1/8)
    unsigned short* kb   = (unsigned short*)(w + 4194304);    // 4 MiB  [B,H,S,Dh]
    unsigned short* vtb  = (unsigned short*)(w + 8388608);    // 4 MiB  [B,H,Dh,S]
    unsigned short* erb  = (unsigned short*)(w + 12582912);   // 128 KiB [1024,64]
    unsigned short* ervT = (unsigned short*)(w + 12713984);   // 136 KiB [64,1088]
    unsigned short* xq   = (unsigned short*)(w + 12853248);   // 4 MiB bf16 X (query)
    unsigned short* xk   = (unsigned short*)(w + 17047552);   // 4 MiB
    unsigned short* xv   = (unsigned short*)(w + 21241856);   // 4 MiB
    unsigned short* wqb  = (unsigned short*)(w + 25436160);   // 2 MiB bf16 W
    unsigned short* wkb  = (unsigned short*)(w + 27533312);   // 2 MiB
    unsigned short* wvb  = (unsigned short*)(w + 29630464);   // 2 MiB (end ~30.3 MiB)

    prep_convert<<<dim3(2048), dim3(256), 0, stream>>>(
        query, key, value, Wq, Wk, Wv, rel, vrel,
        xq, xk, xv, wqb, wkb, wvb, erb, ervT);
    proj_gemm2<<<dim3(768), dim3(256), 0, stream>>>(
        xq, xk, xv, wqb, wkb, wvb, bq, bk, bv, qb, kb, vtb);
    attn_kernel<<<dim3(32, 16, 2), dim3(256), 0, stream>>>(qb, kb, vtb, erb, ervT, out);
}

// Round 11
// 204.419 us; speedup vs baseline: 1.1017x; 1.1017x over previous
//
#include <hip/hip_runtime.h>

typedef __bf16 bf16x8 __attribute__((ext_vector_type(8)));
typedef float f32x4 __attribute__((ext_vector_type(4)));

#define MFMA(a, b, c) __builtin_amdgcn_mfma_f32_16x16x32_bf16((a), (b), (c), 0, 0, 0)

// DPP cross-lane (16-lane row reduce): quad_perm xor1=0xB1, xor2=0x4E, row_ror:4=0x124, row_ror:8=0x128
#define DPPF(x, ctrl) __builtin_bit_cast(float, __builtin_amdgcn_mov_dpp(__builtin_bit_cast(int, (x)), (ctrl), 0xF, 0xF, true))

static __device__ __forceinline__ float rowmax16(float v) {
    v = fmaxf(v, DPPF(v, 0xB1));
    v = fmaxf(v, DPPF(v, 0x4E));
    v = fmaxf(v, DPPF(v, 0x124));
    v = fmaxf(v, DPPF(v, 0x128));
    return v;
}
static __device__ __forceinline__ float rowsum16(float v) {
    v += DPPF(v, 0xB1);
    v += DPPF(v, 0x4E);
    v += DPPF(v, 0x124);
    v += DPPF(v, 0x128);
    return v;
}

static __device__ __forceinline__ unsigned short f2b(float f) {
    // fp32 -> bf16, round-to-nearest-even
    unsigned int u = __builtin_bit_cast(unsigned int, f);
    unsigned int lsb = (u >> 16) & 1u;
    u += 0x7fffu + lsb;
    return (unsigned short)(u >> 16);
}

static __device__ __forceinline__ f32x4 zero4() {
    f32x4 z; z[0] = 0.f; z[1] = 0.f; z[2] = 0.f; z[3] = 0.f; return z;
}

// async global->LDS, 16B per lane; LDS dest = wave-uniform base + lane*16
typedef __attribute__((address_space(3))) unsigned int lds_as_t;
typedef const __attribute__((address_space(1))) unsigned int glb_as_t;
static __device__ __forceinline__ void gload16(const void* g, void* l) {
    __builtin_amdgcn_global_load_lds((glb_as_t*)g, (lds_as_t*)l, 16, 0, 0);
}

// ---------------------------------------------------------------------------
// prep_convert: one BW-bound pass (unchanged from round 8).
// ---------------------------------------------------------------------------
__global__ __launch_bounds__(256) void prep_convert(
    const float* __restrict__ q, const float* __restrict__ k, const float* __restrict__ v,
    const float* __restrict__ wq, const float* __restrict__ wk, const float* __restrict__ wv,
    const float* __restrict__ rel, const float* __restrict__ vrel,
    unsigned short* __restrict__ xq, unsigned short* __restrict__ xk, unsigned short* __restrict__ xv,
    unsigned short* __restrict__ wqb, unsigned short* __restrict__ wkb, unsigned short* __restrict__ wvb,
    unsigned short* __restrict__ erb, unsigned short* __restrict__ ervT)
{
    const int NG = 2375680;  // float4 groups total
    for (int g = blockIdx.x * 256 + threadIdx.x; g < NG + 69632; g += gridDim.x * 256) {
        if (g < NG) {
            const float* src; unsigned short* dst; int off;
            if (g < 1572864) {
                int s = g / 524288; off = g - s * 524288;
                src = s == 0 ? q : s == 1 ? k : v;
                dst = s == 0 ? xq : s == 1 ? xk : xv;
            } else if (g < 2359296) {
                int s = (g - 1572864) / 262144; off = g - 1572864 - s * 262144;
                src = s == 0 ? wq : s == 1 ? wk : wv;
                dst = s == 0 ? wqb : s == 1 ? wkb : wvb;
            } else {
                off = g - 2359296; src = rel; dst = erb;
            }
            float4 x = *(const float4*)(src + (size_t)off * 4);
            *(ushort4*)(dst + (size_t)off * 4) =
                make_ushort4(f2b(x.x), f2b(x.y), f2b(x.z), f2b(x.w));
        } else {
            int j = g - NG;
            int dh = j / 1088, c = j % 1088, r = c - 47;
            ervT[j] = (r >= 0 && r < 1024) ? f2b(vrel[r * 64 + dh]) : (unsigned short)0;
        }
    }
}

// ---------------------------------------------------------------------------
// proj_gemm2: fused M=6144 GEMM (z = mt>>4 selects q/k/v), unchanged.
// ---------------------------------------------------------------------------
__global__ __launch_bounds__(256, 4) void proj_gemm2(
    const unsigned short* __restrict__ xq, const unsigned short* __restrict__ xk,
    const unsigned short* __restrict__ xv,
    const unsigned short* __restrict__ wqb, const unsigned short* __restrict__ wkb,
    const unsigned short* __restrict__ wvb,
    const float* __restrict__ bqp, const float* __restrict__ bkp, const float* __restrict__ bvp,
    unsigned short* __restrict__ oq, unsigned short* __restrict__ ok, unsigned short* __restrict__ ov)
{
    __shared__ unsigned short As[128][64];
    __shared__ unsigned short Bs[64][64];

    const int tid = threadIdx.x, lane = tid & 63, w = tid >> 6;
    const int bid = blockIdx.x;
    const int swz = (bid & 7) * 96 + (bid >> 3);      // bijective XCD swizzle
    const int mt = swz >> 4, nt = swz & 15;
    const int z = mt >> 4;
    const int mm0 = (mt & 15) * 128, n0 = nt * 64;

    const unsigned short* X = z == 0 ? xq : z == 1 ? xk : xv;
    const unsigned short* W = z == 0 ? wqb : z == 1 ? wkb : wvb;
    const float* bias = z == 0 ? bqp : z == 1 ? bkp : bvp;
    unsigned short* outp = z == 0 ? oq : z == 1 ? ok : ov;

    const int wm = (w & 1) * 64, wn = (w >> 1) * 32;
    const int lr = lane & 15, lg = lane >> 4;
    const int arow = lane >> 3, acol = (lane & 7) * 8;

    f32x4 acc[4][2];
#pragma unroll
    for (int a = 0; a < 4; ++a)
#pragma unroll
        for (int bq = 0; bq < 2; ++bq) acc[a][bq] = zero4();

    for (int k0 = 0; k0 < 1024; k0 += 64) {
#pragma unroll
        for (int c = 0; c < 4; ++c) {
            int ch = w + c * 4;
            gload16(X + (size_t)(mm0 + ch * 8 + arow) * 1024 + k0 + acol, &As[ch * 8][0]);
        }
#pragma unroll
        for (int c = 0; c < 2; ++c) {
            int ch = w + c * 4;
            gload16(W + (size_t)(n0 + ch * 8 + arow) * 1024 + k0 + acol, &Bs[ch * 8][0]);
        }
        __syncthreads();

        bf16x8 af[4][2], bg[2][2];
#pragma unroll
        for (int m4 = 0; m4 < 4; ++m4)
#pragma unroll
            for (int ks = 0; ks < 2; ++ks)
                af[m4][ks] = *(const bf16x8*)&As[wm + m4 * 16 + lr][ks * 32 + lg * 8];
#pragma unroll
        for (int n2 = 0; n2 < 2; ++n2)
#pragma unroll
            for (int ks = 0; ks < 2; ++ks)
                bg[n2][ks] = *(const bf16x8*)&Bs[wn + n2 * 16 + lr][ks * 32 + lg * 8];
#pragma unroll
        for (int m4 = 0; m4 < 4; ++m4)
#pragma unroll
            for (int n2 = 0; n2 < 2; ++n2)
#pragma unroll
                for (int ks = 0; ks < 2; ++ks)
                    acc[m4][n2] = MFMA(af[m4][ks], bg[n2][ks], acc[m4][n2]);
        __syncthreads();
    }

#pragma unroll
    for (int m4 = 0; m4 < 4; ++m4)
#pragma unroll
        for (int n2 = 0; n2 < 2; ++n2)
#pragma unroll
            for (int r = 0; r < 4; ++r) {
                int mrow = mm0 + wm + m4 * 16 + lg * 4 + r;
                int n = n0 + wn + n2 * 16 + lr;
                float vv = acc[m4][n2][r] + bias[n];
                if (z == 0) vv *= 0.125f;          // fold score scale into Q (exact)
                int b = mrow >> 10, s = mrow & 1023, h = n >> 6, dh = n & 63;
                unsigned short bv = f2b(vv);
                if (z == 2)
                    outp[(((size_t)(b * 16 + h)) * 64 + dh) * 1024 + s] = bv;
                else
                    outp[(((size_t)(b * 16 + h)) * 1024 + s) * 64 + dh] = bv;
            }
}

// ---------------------------------------------------------------------------
// Fused causal attention with relative-position bias (scores and values).
// Round-11: 64-column iterations (2 KV tiles fused) -> per unit of work the
// fixed costs halve: 1 softmax update, 2 LDS round trips, 1 batched load
// group (38 x b128 issued together at iteration top). No cross-iteration
// prefetch (R10: cost occupancy). Paired q-tiles (qt, 63-qt): 17 pair-iters
// per block uniformly, 4 waves split them (4.25 each).
// Slot algebra (64-col): t = row - jcol + 63 in [0,78]; d = dbp2 + t,
// dbp2 = i0 - j0 - 63. QE: 5 tiles cover t in [0,80). PR: [16][96], 3 K=32
// MFMAs per dt. Tail tiles/columns are causally masked; their OOB reads stay
// inside d_ws (finite bf16) and P=0 kills the contribution.
// Q arrives pre-scaled by 0.125 from proj (exact).
// ---------------------------------------------------------------------------
__global__ __launch_bounds__(256, 1) void attn_kernel(
    const unsigned short* __restrict__ qb, const unsigned short* __restrict__ kb,
    const unsigned short* __restrict__ vtb, const unsigned short* __restrict__ erb,
    const unsigned short* __restrict__ ervT, float* __restrict__ out)
{
    const int bx = blockIdx.x, h = blockIdx.y, b = blockIdx.z;
    const int bh = b * 16 + h;
    const int tid = threadIdx.x;
    const int lane = tid & 63, w = tid >> 6;
    const int lr = lane & 15, lg = lane >> 4;

    // Layout: [0,20480) qe (4 x [16][80] f32) | [20480,28672) p (4 x [16][64] u16)
    //         [28672,29184) pm/pl | [29184,41472) prv (4 x [16][96] u16)
    // Combine-phase pO = [0,16384) f32 (after barrier; never touches pm/pl/prv).
    __shared__ __align__(16) char smem[41472];
    float* qe_w = (float*)(smem + w * 5120);                             // [16][80]
    unsigned short* p_w   = (unsigned short*)(smem + 20480 + w * 2048);  // [16][64]
    unsigned short* prv_w = (unsigned short*)(smem + 29184 + w * 3072);  // [16][96]
    float* pO = (float*)smem;              // [4][16][64]
    float* pm = (float*)(smem + 28672);    // [4][16]
    float* pl = pm + 64;                   // [4][16]

    // zero own prv slice once; slots outside [row,row+63] stay zero forever
    for (int t = lane; t < 16 * 96; t += 64) prv_w[t] = 0;

    for (int seg = 0; seg < 2; ++seg) {
        const int qt = seg == 0 ? bx : 63 - bx;
        const int i0 = qt * 16;

        const unsigned short* qbase = qb + (((size_t)bh * 1024) + i0 + lr) * 64 + lg * 8;
        const bf16x8 qf0 = *(const bf16x8*)qbase;         // dh 0..31 (pre-scaled 1/8)
        const bf16x8 qf1 = *(const bf16x8*)(qbase + 32);  // dh 32..63

        f32x4 oacc[4];
        float m_run[4], l_run[4];
#pragma unroll
        for (int r = 0; r < 4; ++r) { oacc[r] = zero4(); m_run[r] = -1e30f; l_run[r] = 0.f; }

        const int ntiles = qt / 2 + 1;          // 32-col tiles
        const int npairs = (ntiles + 1) >> 1;   // 64-col iterations
        for (int ti2 = w; ti2 < npairs; ti2 += 4) {
            const int j0 = ti2 * 64;
            const int dbp2 = i0 - j0 - 63;      // distance of slot t=0

            // ---- one batched load group: 38 x b128 ----------------------
            bf16x8 kf[4][2], ef[5][2], vf[4][2], rf[4][3];
#pragma unroll
            for (int ct = 0; ct < 4; ++ct) {
                const unsigned short* kbase =
                    kb + (((size_t)bh * 1024) + j0 + ct * 16 + lr) * 64 + lg * 8;
                kf[ct][0] = *(const bf16x8*)kbase;
                kf[ct][1] = *(const bf16x8*)(kbase + 32);
            }
#pragma unroll
            for (int st = 0; st < 5; ++st) {
                int dr = dbp2 + st * 16 + lr;
                dr = dr < 0 ? 0 : (dr > 1023 ? 1023 : dr);  // clamped rows feed masked slots only
                const unsigned short* eb = erb + (size_t)dr * 64 + lg * 8;
                ef[st][0] = *(const bf16x8*)eb;
                ef[st][1] = *(const bf16x8*)(eb + 32);
            }
#pragma unroll
            for (int dt = 0; dt < 4; ++dt)
#pragma unroll
                for (int ks = 0; ks < 2; ++ks)
                    vf[dt][ks] = *(const bf16x8*)(vtb + ((size_t)bh * 64 + dt * 16 + lr) * 1024
                                                  + j0 + ks * 32 + lg * 8);
#pragma unroll
            for (int dt = 0; dt < 4; ++dt)
#pragma unroll
                for (int ks = 0; ks < 3; ++ks)
                    rf[dt][ks] = *(const bf16x8*)(ervT + (size_t)(dt * 16 + lr) * 1088
                                                  + 47 + dbp2 + ks * 32 + lg * 8);

            // ---- QK^T: four 16x16 score tiles ---------------------------
            f32x4 sacc[4];
#pragma unroll
            for (int ct = 0; ct < 4; ++ct) {
                sacc[ct] = zero4();
                sacc[ct] = MFMA(qf0, kf[ct][0], sacc[ct]);
                sacc[ct] = MFMA(qf1, kf[ct][1], sacc[ct]);
            }

            // ---- QE: q . er[dbp2 + t], t in [0,80) ----------------------
            f32x4 qeacc[5];
#pragma unroll
            for (int st = 0; st < 5; ++st) {
                qeacc[st] = zero4();
                qeacc[st] = MFMA(qf0, ef[st][0], qeacc[st]);
                qeacc[st] = MFMA(qf1, ef[st][1], qeacc[st]);
            }

            // ---- scatter qe bias to own LDS ([16][80] f32) --------------
#pragma unroll
            for (int st = 0; st < 5; ++st)
#pragma unroll
                for (int r = 0; r < 4; ++r)
                    qe_w[(lg * 4 + r) * 80 + st * 16 + lr] = qeacc[st][r];

            // ---- gather bias, mask --------------------------------------
            float sc2[4][4];
#pragma unroll
            for (int ct = 0; ct < 4; ++ct)
#pragma unroll
                for (int r = 0; r < 4; ++r) {
                    int row  = lg * 4 + r;
                    int jcol = ct * 16 + lr;
                    int t    = row - jcol + 63;             // slot in [0,78]
                    float sc = sacc[ct][r] + qe_w[row * 80 + t];
                    if (j0 + jcol > i0 + row) sc = -1e38f;  // causal mask
                    sc2[ct][r] = sc;
                }

            // ---- online softmax over 64 cols (one update) ---------------
            float p2[4][4];
#pragma unroll
            for (int r = 0; r < 4; ++r) {
                float mx = fmaxf(fmaxf(sc2[0][r], sc2[1][r]), fmaxf(sc2[2][r], sc2[3][r]));
                mx = rowmax16(mx);
                float mnew = fmaxf(m_run[r], mx);
                float scale = __expf(m_run[r] - mnew);
                float p0 = __expf(sc2[0][r] - mnew);
                float p1 = __expf(sc2[1][r] - mnew);
                float p2_ = __expf(sc2[2][r] - mnew);
                float p3 = __expf(sc2[3][r] - mnew);
                float ps = rowsum16((p0 + p1) + (p2_ + p3));
                l_run[r] = l_run[r] * scale + ps;
                m_run[r] = mnew;
#pragma unroll
                for (int dt = 0; dt < 4; ++dt) oacc[dt][r] *= scale;
                p2[0][r] = p0; p2[1][r] = p1; p2[2][r] = p2_; p2[3][r] = p3;
            }

            // ---- write P (normal + column-reversed) to own LDS slices ---
#pragma unroll
            for (int ct = 0; ct < 4; ++ct)
#pragma unroll
                for (int r = 0; r < 4; ++r) {
                    int row = lg * 4 + r, col = ct * 16 + lr;
                    unsigned short pb = f2b(p2[ct][r]);
                    p_w[row * 64 + col] = pb;
                    prv_w[row * 96 + (row + 63 - col)] = pb;  // slot t in [row, row+63]
                }

            // ---- PV + PR@Erv --------------------------------------------
            bf16x8 pa0  = *(const bf16x8*)&p_w[lr * 64 + lg * 8];
            bf16x8 pa1  = *(const bf16x8*)&p_w[lr * 64 + 32 + lg * 8];
            bf16x8 pra0 = *(const bf16x8*)&prv_w[lr * 96 + lg * 8];        // slots 0..31
            bf16x8 pra1 = *(const bf16x8*)&prv_w[lr * 96 + 32 + lg * 8];   // slots 32..63
            bf16x8 pra2 = *(const bf16x8*)&prv_w[lr * 96 + 64 + lg * 8];   // slots 64..95
#pragma unroll
            for (int dt = 0; dt < 4; ++dt) {
                oacc[dt] = MFMA(pa0, vf[dt][0], oacc[dt]);
                oacc[dt] = MFMA(pa1, vf[dt][1], oacc[dt]);
                oacc[dt] = MFMA(pra0, rf[dt][0], oacc[dt]);
                oacc[dt] = MFMA(pra1, rf[dt][1], oacc[dt]);
                oacc[dt] = MFMA(pra2, rf[dt][2], oacc[dt]);
            }
        }

        // ---- merge the 4 wave-partials via LDS --------------------------
        __syncthreads();  // loop-phase LDS reads done before pO overwrites
#pragma unroll
        for (int dt = 0; dt < 4; ++dt)
#pragma unroll
            for (int r = 0; r < 4; ++r)
                pO[w * 1024 + (lg * 4 + r) * 64 + dt * 16 + lr] = oacc[dt][r];
        if (lr == 0)
#pragma unroll
            for (int r = 0; r < 4; ++r) {
                pm[w * 16 + lg * 4 + r] = m_run[r];
                pl[w * 16 + lg * 4 + r] = l_run[r];
            }
        __syncthreads();

        // 16x64 outputs over 256 threads (4 cells each)
#pragma unroll
        for (int k = 0; k < 4; ++k) {
            int c = k * 256 + tid;
            int row = c >> 6, dh = c & 63;
            float m0 = pm[row], m1 = pm[16 + row], m2 = pm[32 + row], m3 = pm[48 + row];
            float mf = fmaxf(fmaxf(m0, m1), fmaxf(m2, m3));
            float e0 = __expf(m0 - mf), e1 = __expf(m1 - mf);
            float e2 = __expf(m2 - mf), e3 = __expf(m3 - mf);
            float den = e0 * pl[row] + e1 * pl[16 + row] + e2 * pl[32 + row] + e3 * pl[48 + row];
            float num = e0 * pO[row * 64 + dh]        + e1 * pO[1024 + row * 64 + dh]
                      + e2 * pO[2048 + row * 64 + dh] + e3 * pO[3072 + row * 64 + dh];
            out[((size_t)(b * 1024 + i0 + row)) * 1024 + h * 64 + dh] = num / den;
        }
        __syncthreads();  // pO reads done before next segment's qe writes
    }
}

// ---------------------------------------------------------------------------
extern "C" void kernel_launch(void* const* d_in, const int* in_sizes, int n_in,
                              void* d_out, int out_size, void* d_ws, size_t ws_size,
                              hipStream_t stream) {
    const float* query = (const float*)d_in[0];
    const float* key   = (const float*)d_in[1];
    const float* value = (const float*)d_in[2];
    const float* Wq    = (const float*)d_in[3];
    const float* bq    = (const float*)d_in[4];
    const float* Wk    = (const float*)d_in[5];
    const float* bk    = (const float*)d_in[6];
    const float* Wv    = (const float*)d_in[7];
    const float* bv    = (const float*)d_in[8];
    const float* rel   = (const float*)d_in[9];
    const float* vrel  = (const float*)d_in[10];
    float* out = (float*)d_out;

    char* w = (char*)d_ws;
    unsigned short* qb   = (unsigned short*)(w);              // 4 MiB  [B,H,S,Dh] (Q pre-scaled 1/8)
    unsigned short* kb   = (unsigned short*)(w + 4194304);    // 4 MiB  [B,H,S,Dh]
    unsigned short* vtb  = (unsigned short*)(w + 8388608);    // 4 MiB  [B,H,Dh,S]
    unsigned short* erb  = (unsigned short*)(w + 12582912);   // 128 KiB [1024,64]
    unsigned short* ervT = (unsigned short*)(w + 12713984);   // 136 KiB [64,1088]
    unsigned short* xq   = (unsigned short*)(w + 12853248);   // 4 MiB bf16 X (query)
    unsigned short* xk   = (unsigned short*)(w + 17047552);   // 4 MiB
    unsigned short* xv   = (unsigned short*)(w + 21241856);   // 4 MiB
    unsigned short* wqb  = (unsigned short*)(w + 25436160);   // 2 MiB bf16 W
    unsigned short* wkb  = (unsigned short*)(w + 27533312);   // 2 MiB
    unsigned short* wvb  = (unsigned short*)(w + 29630464);   // 2 MiB (end ~30.3 MiB)

    prep_convert<<<dim3(2048), dim3(256), 0, stream>>>(
        query, key, value, Wq, Wk, Wv, rel, vrel,
        xq, xk, xv, wqb, wkb, wvb, erb, ervT);
    proj_gemm2<<<dim3(768), dim3(256), 0, stream>>>(
        xq, xk, xv, wqb, wkb, wvb, bq, bk, bv, qb, kb, vtb);
    attn_kernel<<<dim3(32, 16, 2), dim3(256), 0, stream>>>(qb, kb, vtb, erb, ervT, out);
}